// Round 5
// baseline (135.258 us; speedup 1.0000x reference)
//
#include <hip/hip_runtime.h>
#include <hip/hip_bf16.h>
#include <cstdint>

using u16 = unsigned short;
using u32 = unsigned int;

#define DEPTH 10
#define NF 512
#define NL 1024
#define BATCH_N 32768
#define TEMP_INV 10.0f
#define GBM 128
#define GBN 256
#define GBK 32
#define NSTEP 32

typedef float f32x4 __attribute__((ext_vector_type(4)));
typedef short s16x8 __attribute__((ext_vector_type(8)));
typedef __bf16 bf16x8 __attribute__((ext_vector_type(8)));

__device__ __forceinline__ u16 f2bf(float f) {
  u32 u = __float_as_uint(f);
  u = (u + 0x7fffu + ((u >> 16) & 1u)) >> 16;
  return (u16)u;
}

__device__ __forceinline__ void gld_lds16(const void* g, void* lds) {
  __builtin_amdgcn_global_load_lds(
      (const __attribute__((address_space(1))) void*)g,
      (__attribute__((address_space(3))) void*)lds, 16, 0, 0);
}

// ---------------- kernel 1: softmax(feature_weights) -> probs (10x512 f32)
__global__ void k_softmax(const float* __restrict__ fw, float* __restrict__ probs) {
  int w = threadIdx.x >> 6;
  int lane = threadIdx.x & 63;
  if (w >= DEPTH) return;
  const float* row = fw + w * NF;
  float v[8];
  float mx = -1e30f;
#pragma unroll
  for (int i = 0; i < 8; ++i) { v[i] = row[lane * 8 + i]; mx = fmaxf(mx, v[i]); }
#pragma unroll
  for (int s = 32; s >= 1; s >>= 1) mx = fmaxf(mx, __shfl_xor(mx, s));
  float sum = 0.f;
#pragma unroll
  for (int i = 0; i < 8; ++i) { v[i] = __expf(v[i] - mx); sum += v[i]; }
#pragma unroll
  for (int s = 32; s >= 1; s >>= 1) sum += __shfl_xor(sum, s);
  float inv = 1.0f / sum;
#pragma unroll
  for (int i = 0; i < 8; ++i) probs[w * NF + lane * 8 + i] = v[i] * inv;
}

// ---------------- kernel 2: leaf_values f32 (512x1024) -> bf16 (same layout)
__global__ void k_cvt(const float* __restrict__ lv, u16* __restrict__ lvb) {
  int i = (blockIdx.x * blockDim.x + threadIdx.x) * 8;
  float4 a = *(const float4*)(lv + i);
  float4 b = *(const float4*)(lv + i + 4);
  uint4 u;
  u.x = f2bf(a.x) | ((u32)f2bf(a.y) << 16);
  u.y = f2bf(a.z) | ((u32)f2bf(a.w) << 16);
  u.z = f2bf(b.x) | ((u32)f2bf(b.y) << 16);
  u.w = f2bf(b.z) | ((u32)f2bf(b.w) << 16);
  *(uint4*)(lvb + i) = u;
}

// ---------------- kernel 3: sel = x@probs.T -> sigmoid -> p[32768][10] f32
// 8 threads per row (q-split), coalesced 128B/row-group, high occupancy.
__global__ __launch_bounds__(256) void k_sel(const float* __restrict__ x,
                                             const float* __restrict__ probs,
                                             const float* __restrict__ thr,
                                             float* __restrict__ pout) {
  __shared__ float Ps[DEPTH * NF];
  const int tid = threadIdx.x;
  for (int i = tid; i < DEPTH * NF; i += 256) Ps[i] = probs[i];
  __syncthreads();
  const int q = tid & 7;
  const int row = blockIdx.x * 32 + (tid >> 3);
  const float* xr = x + (size_t)row * NF + q * 4;
  float acc[DEPTH];
#pragma unroll
  for (int d = 0; d < DEPTH; ++d) acc[d] = 0.f;
#pragma unroll
  for (int i = 0; i < 16; ++i) {
    float4 xv = *(const float4*)(xr + i * 32);
#pragma unroll
    for (int d = 0; d < DEPTH; ++d) {
      f32x4 pv = *(const f32x4*)&Ps[d * NF + i * 32 + q * 4];
      acc[d] += xv.x * pv[0] + xv.y * pv[1] + xv.z * pv[2] + xv.w * pv[3];
    }
  }
#pragma unroll
  for (int d = 0; d < DEPTH; ++d) {
    float s = acc[d];
    s += __shfl_xor(s, 1);
    s += __shfl_xor(s, 2);
    s += __shfl_xor(s, 4);
    float pd = 1.0f / (1.0f + __expf(-(s - thr[d]) * TEMP_INV));
    if (q == (d & 7)) pout[(size_t)row * DEPTH + d] = pd;  // d=8,9 -> lanes 0,1
  }
}

// ---------------- kernel 4: GEMM  C[128x256 tile] = leafprob(gen) @ lvb^T
// Block: 128 rows x 256 cols (N-split 2) -> 512 blocks, 2/CU. A generated from
// p into swizzled LDS ((r>>1)&3 XOR -> 2-way banks, free). B double-buffered
// via global_load_lds with inverse-swizzled source. Wave tile 64x128.
__global__ __launch_bounds__(256, 2) void k_gemm(const u16* __restrict__ B,
                                                 const float* __restrict__ p,
                                                 float* __restrict__ C) {
  __shared__ char smem[49152];  // As: 2x8KB @0, Bs: 2x16KB @16384
  const int tid = threadIdx.x;
  const int lane = tid & 63;
  const int w = tid >> 6;       // 0..3
  const int wm = w >> 1, wn = w & 1;
  const int bm = blockIdx.x >> 1, bn = blockIdx.x & 1;
  const int brow = bm * GBM, bcol = bn * GBN;

  // ---- A-generator identity: thread owns row gr, leaf-half gh ----
  const int gr = tid >> 1;   // 0..127
  const int gh = tid & 1;    // leaf bit b4 (d=5)
  const float* prw = p + (size_t)(brow + gr) * DEPTH;
  float pv[10];
#pragma unroll
  for (int d = 0; d < 10; ++d) pv[d] = prw[d];
  // T[i] over leaf low bits: b4=gh(d5), b3=i&8(d6), b2=i&4(d7), b1=i&2(d8), b0=i&1(d9)
  float T[16];
  {
    float s5 = gh ? pv[5] : 1.f - pv[5];
    float a6 = 1.f - pv[6], b6 = pv[6], a7 = 1.f - pv[7], b7 = pv[7];
    float a8 = 1.f - pv[8], b8 = pv[8], a9 = 1.f - pv[9], b9 = pv[9];
    float m67[4] = {a6 * a7, a6 * b7, b6 * a7, b6 * b7};
    float m89[4] = {a8 * a9, a8 * b9, b8 * a9, b8 * b9};
#pragma unroll
    for (int i = 0; i < 16; ++i) T[i] = s5 * m67[i >> 2] * m89[i & 3];
  }
  const float p0a = 1.f - pv[0], p0b = pv[0], p1a = 1.f - pv[1], p1b = pv[1],
              p2a = 1.f - pv[2], p2b = pv[2], p3a = 1.f - pv[3], p3b = pv[3],
              p4a = 1.f - pv[4], p4b = pv[4];

  const int xorg = (gr >> 1) & 3;
  const int wb0 = gr * 64 + (((gh * 2)     ^ xorg) << 4);
  const int wb1 = gr * 64 + (((gh * 2 + 1) ^ xorg) << 4);

  f32x4 acc[4][8];
#pragma unroll
  for (int m = 0; m < 4; ++m)
#pragma unroll
    for (int n = 0; n < 8; ++n) acc[m][n] = {0.f, 0.f, 0.f, 0.f};

  auto STAGE = [&](int step, int buf) {
    char* bsb = smem + 16384 + buf * 16384;
#pragma unroll
    for (int it = 0; it < 4; ++it) {
      int lin = it * 256 + tid;
      int r = lin >> 2;
      int slog = (lin & 3) ^ ((r >> 1) & 3);
      gld_lds16(B + (size_t)(bcol + r) * NL + step * GBK + slog * 8, bsb + lin * 16);
    }
  };
  auto GENA = [&](int step, int buf) {
    // leaf = step*32 + l ; high bits: b9=step&16(d0) ... b5=step&1(d4)
    float H = ((step & 16) ? p0b : p0a) * ((step & 8) ? p1b : p1a);
    H *= (step & 4) ? p2b : p2a;
    H *= (step & 2) ? p3b : p3a;
    H *= (step & 1) ? p4b : p4a;
    bf16x8 v0, v1;
#pragma unroll
    for (int j = 0; j < 8; ++j) {
      v0[j] = (__bf16)(H * T[j]);
      v1[j] = (__bf16)(H * T[8 + j]);
    }
    char* asb = smem + buf * 8192;
    *(bf16x8*)(asb + wb0) = v0;
    *(bf16x8*)(asb + wb1) = v1;
  };

  STAGE(0, 0);
  GENA(0, 0);
  asm volatile("s_waitcnt vmcnt(0) lgkmcnt(0)" ::: "memory");
  __builtin_amdgcn_s_barrier();

  const int rA = lane & 15, sg = lane >> 4;
  const int soff = (sg ^ ((rA >> 1) & 3)) << 4;
  const int aoff = (wm * 64 + rA) * 64 + soff;   // + m*1024 bytes
  const int boff = (wn * 128 + rA) * 64 + soff;  // + n*1024 bytes

  for (int kk = 0; kk < NSTEP; ++kk) {
    const int cur = kk & 1;
    if (kk + 1 < NSTEP) {
      STAGE(kk + 1, cur ^ 1);
      GENA(kk + 1, cur ^ 1);
    }
    const char* ab = smem + cur * 8192;
    const char* bb = smem + 16384 + cur * 16384;
    bf16x8 a[4];
#pragma unroll
    for (int m = 0; m < 4; ++m)
      a[m] = __builtin_bit_cast(bf16x8, *(const s16x8*)(ab + aoff + m * 1024));
#pragma unroll
    for (int n = 0; n < 8; ++n) {
      bf16x8 bf = __builtin_bit_cast(bf16x8, *(const s16x8*)(bb + boff + n * 1024));
      acc[0][n] = __builtin_amdgcn_mfma_f32_16x16x32_bf16(a[0], bf, acc[0][n], 0, 0, 0);
      acc[1][n] = __builtin_amdgcn_mfma_f32_16x16x32_bf16(a[1], bf, acc[1][n], 0, 0, 0);
      acc[2][n] = __builtin_amdgcn_mfma_f32_16x16x32_bf16(a[2], bf, acc[2][n], 0, 0, 0);
      acc[3][n] = __builtin_amdgcn_mfma_f32_16x16x32_bf16(a[3], bf, acc[3][n], 0, 0, 0);
    }
    asm volatile("s_waitcnt vmcnt(0) lgkmcnt(0)" ::: "memory");
    __builtin_amdgcn_s_barrier();
  }

  // ---- epilogue: C/D map col=lane&15, row=(lane>>4)*4+reg ----
  const int c0 = lane & 15;
  const int r0 = (lane >> 4) * 4;
#pragma unroll
  for (int m = 0; m < 4; ++m)
#pragma unroll
    for (int n = 0; n < 8; ++n) {
      int col = bcol + wn * 128 + n * 16 + c0;
#pragma unroll
      for (int r = 0; r < 4; ++r)
        C[(size_t)(brow + wm * 64 + m * 16 + r0 + r) * NF + col] = acc[m][n][r];
    }
}

extern "C" void kernel_launch(void* const* d_in, const int* in_sizes, int n_in,
                              void* d_out, int out_size, void* d_ws, size_t ws_size,
                              hipStream_t stream) {
  const float* x  = (const float*)d_in[0];
  const float* fw = (const float*)d_in[1];
  const float* th = (const float*)d_in[2];
  const float* lv = (const float*)d_in[3];
  float* out = (float*)d_out;

  float* probs = (float*)d_ws;                           // 20 KB
  u16* lvb = (u16*)((char*)d_ws + DEPTH * NF * 4);       // 1 MB
  float* pbuf = (float*)((char*)d_ws + DEPTH * NF * 4 + NF * NL * 2);  // 1.3 MB

  k_softmax<<<1, 640, 0, stream>>>(fw, probs);
  k_cvt<<<(NF * NL / 8) / 256, 256, 0, stream>>>(lv, lvb);
  k_sel<<<BATCH_N / 32, 256, 0, stream>>>(x, probs, th, pbuf);
  k_gemm<<<(BATCH_N / GBM) * 2, 256, 0, stream>>>(lvb, pbuf, out);
}

// Round 6
// 80.452 us; speedup vs baseline: 1.6812x; 1.6812x over previous
//
#include <hip/hip_runtime.h>
#include <hip/hip_bf16.h>
#include <cstdint>

using u16 = unsigned short;
using u32 = unsigned int;

#define DEPTH 10
#define NF 512
#define NL 1024
#define BATCH_N 32768
#define TEMP_INV 10.0f
#define GBM 128
#define GBN 256
#define GBK 32
#define NSTEP 32

typedef float f32x4 __attribute__((ext_vector_type(4)));
typedef short s16x8 __attribute__((ext_vector_type(8)));
typedef __bf16 bf16x8 __attribute__((ext_vector_type(8)));

__device__ __forceinline__ u16 f2bf(float f) {
  u32 u = __float_as_uint(f);
  u = (u + 0x7fffu + ((u >> 16) & 1u)) >> 16;
  return (u16)u;
}

__device__ __forceinline__ void gld_lds16(const void* g, void* lds) {
  __builtin_amdgcn_global_load_lds(
      (const __attribute__((address_space(1))) void*)g,
      (__attribute__((address_space(3))) void*)lds, 16, 0, 0);
}

// ---------------- kernel 1: softmax(feature_weights) -> probs (10x512 f32)
__global__ void k_softmax(const float* __restrict__ fw, float* __restrict__ probs) {
  int w = threadIdx.x >> 6;
  int lane = threadIdx.x & 63;
  if (w >= DEPTH) return;
  const float* row = fw + w * NF;
  float v[8];
  float mx = -1e30f;
#pragma unroll
  for (int i = 0; i < 8; ++i) { v[i] = row[lane * 8 + i]; mx = fmaxf(mx, v[i]); }
#pragma unroll
  for (int s = 32; s >= 1; s >>= 1) mx = fmaxf(mx, __shfl_xor(mx, s));
  float sum = 0.f;
#pragma unroll
  for (int i = 0; i < 8; ++i) { v[i] = __expf(v[i] - mx); sum += v[i]; }
#pragma unroll
  for (int s = 32; s >= 1; s >>= 1) sum += __shfl_xor(sum, s);
  float inv = 1.0f / sum;
#pragma unroll
  for (int i = 0; i < 8; ++i) probs[w * NF + lane * 8 + i] = v[i] * inv;
}

// ---------------- kernel 2: leaf_values f32 (512x1024) -> bf16 (same layout)
__global__ void k_cvt(const float* __restrict__ lv, u16* __restrict__ lvb) {
  int i = (blockIdx.x * blockDim.x + threadIdx.x) * 8;
  float4 a = *(const float4*)(lv + i);
  float4 b = *(const float4*)(lv + i + 4);
  uint4 u;
  u.x = f2bf(a.x) | ((u32)f2bf(a.y) << 16);
  u.y = f2bf(a.z) | ((u32)f2bf(a.w) << 16);
  u.z = f2bf(b.x) | ((u32)f2bf(b.y) << 16);
  u.w = f2bf(b.z) | ((u32)f2bf(b.w) << 16);
  *(uint4*)(lvb + i) = u;
}

// ---------------- kernel 3: sel = x@probs.T -> sigmoid -> p[32768][10] f32
// 16 lanes per row (g owns 32 features), 4 rows/wave, 4-level shfl reduce.
// Ps in LDS with pitch-36 pad per 32-float group: bank 4(g+i)%32 -> 2-way (free).
__global__ __launch_bounds__(256, 6) void k_sel(const float* __restrict__ x,
                                                const float* __restrict__ probs,
                                                const float* __restrict__ thr,
                                                float* __restrict__ pout) {
  __shared__ float Ps[DEPTH * 576];  // [10][16 groups][36] -> 23040 B
  const int tid = threadIdx.x;
#pragma unroll
  for (int d = 0; d < DEPTH; ++d)
    for (int f = tid; f < NF; f += 256)
      Ps[d * 576 + (f >> 5) * 36 + (f & 31)] = probs[d * NF + f];
  __syncthreads();

  const int lane = tid & 63;
  const int w = tid >> 6;
  const int g = lane & 15;   // feature group
  const int qr = lane >> 4;  // row within wave
  const int row = blockIdx.x * 16 + w * 4 + qr;
  const float* xr = x + (size_t)row * NF + g * 32;

  float a0 = 0.f, a1 = 0.f, a2 = 0.f, a3 = 0.f, a4 = 0.f;
  float a5 = 0.f, a6 = 0.f, a7 = 0.f, a8 = 0.f, a9 = 0.f;
#pragma unroll
  for (int i = 0; i < 8; ++i) {
    float4 xv = *(const float4*)(xr + i * 4);
    const float* pb = &Ps[g * 36 + i * 4];
#define ACCD(D, A)                                                   \
    {                                                                \
      f32x4 pv = *(const f32x4*)(pb + (D) * 576);                    \
      A += xv.x * pv[0] + xv.y * pv[1] + xv.z * pv[2] + xv.w * pv[3];\
    }
    ACCD(0, a0) ACCD(1, a1) ACCD(2, a2) ACCD(3, a3) ACCD(4, a4)
    ACCD(5, a5) ACCD(6, a6) ACCD(7, a7) ACCD(8, a8) ACCD(9, a9)
#undef ACCD
  }
#define RED(A)                      \
  A += __shfl_xor(A, 1);            \
  A += __shfl_xor(A, 2);            \
  A += __shfl_xor(A, 4);            \
  A += __shfl_xor(A, 8);
  RED(a0) RED(a1) RED(a2) RED(a3) RED(a4)
  RED(a5) RED(a6) RED(a7) RED(a8) RED(a9)
#undef RED
  if (g < DEPTH) {
    float s = (g == 0) ? a0 : (g == 1) ? a1 : (g == 2) ? a2 : (g == 3) ? a3
            : (g == 4) ? a4 : (g == 5) ? a5 : (g == 6) ? a6 : (g == 7) ? a7
            : (g == 8) ? a8 : a9;
    float pd = 1.0f / (1.0f + __expf(-(s - thr[g]) * TEMP_INV));
    pout[(size_t)row * DEPTH + g] = pd;
  }
}

// ---------------- kernel 4: GEMM  C[128x256 tile] = leafprob(gen) @ lvb^T
// Block: 128 rows x 256 cols (N-split 2) -> 512 blocks, 2/CU. A generated from
// p into swizzled LDS ((r>>1)&3 XOR -> 2-way banks, free). B double-buffered
// via global_load_lds with inverse-swizzled source. Wave tile 64x128.
__global__ __launch_bounds__(256, 2) void k_gemm(const u16* __restrict__ B,
                                                 const float* __restrict__ p,
                                                 float* __restrict__ C) {
  __shared__ char smem[49152];  // As: 2x8KB @0, Bs: 2x16KB @16384
  const int tid = threadIdx.x;
  const int lane = tid & 63;
  const int w = tid >> 6;       // 0..3
  const int wm = w >> 1, wn = w & 1;
  const int bm = blockIdx.x >> 1, bn = blockIdx.x & 1;
  const int brow = bm * GBM, bcol = bn * GBN;

  // ---- A-generator identity: thread owns row gr, leaf-half gh ----
  const int gr = tid >> 1;   // 0..127
  const int gh = tid & 1;    // leaf bit b4 (d=5)
  const float* prw = p + (size_t)(brow + gr) * DEPTH;
  float pv[10];
#pragma unroll
  for (int d = 0; d < 10; ++d) pv[d] = prw[d];
  // T[i] over leaf low bits: b4=gh(d5), b3=i&8(d6), b2=i&4(d7), b1=i&2(d8), b0=i&1(d9)
  float T[16];
  {
    float s5 = gh ? pv[5] : 1.f - pv[5];
    float a6 = 1.f - pv[6], b6 = pv[6], a7 = 1.f - pv[7], b7 = pv[7];
    float a8 = 1.f - pv[8], b8 = pv[8], a9 = 1.f - pv[9], b9 = pv[9];
    float m67[4] = {a6 * a7, a6 * b7, b6 * a7, b6 * b7};
    float m89[4] = {a8 * a9, a8 * b9, b8 * a9, b8 * b9};
#pragma unroll
    for (int i = 0; i < 16; ++i) T[i] = s5 * m67[i >> 2] * m89[i & 3];
  }
  const float p0a = 1.f - pv[0], p0b = pv[0], p1a = 1.f - pv[1], p1b = pv[1],
              p2a = 1.f - pv[2], p2b = pv[2], p3a = 1.f - pv[3], p3b = pv[3],
              p4a = 1.f - pv[4], p4b = pv[4];

  const int xorg = (gr >> 1) & 3;
  const int wb0 = gr * 64 + (((gh * 2)     ^ xorg) << 4);
  const int wb1 = gr * 64 + (((gh * 2 + 1) ^ xorg) << 4);

  f32x4 acc[4][8];
#pragma unroll
  for (int m = 0; m < 4; ++m)
#pragma unroll
    for (int n = 0; n < 8; ++n) acc[m][n] = {0.f, 0.f, 0.f, 0.f};

  auto STAGE = [&](int step, int buf) {
    char* bsb = smem + 16384 + buf * 16384;
#pragma unroll
    for (int it = 0; it < 4; ++it) {
      int lin = it * 256 + tid;
      int r = lin >> 2;
      int slog = (lin & 3) ^ ((r >> 1) & 3);
      gld_lds16(B + (size_t)(bcol + r) * NL + step * GBK + slog * 8, bsb + lin * 16);
    }
  };
  auto GENA = [&](int step, int buf) {
    // leaf = step*32 + l ; high bits: b9=step&16(d0) ... b5=step&1(d4)
    float H = ((step & 16) ? p0b : p0a) * ((step & 8) ? p1b : p1a);
    H *= (step & 4) ? p2b : p2a;
    H *= (step & 2) ? p3b : p3a;
    H *= (step & 1) ? p4b : p4a;
    bf16x8 v0, v1;
#pragma unroll
    for (int j = 0; j < 8; ++j) {
      v0[j] = (__bf16)(H * T[j]);
      v1[j] = (__bf16)(H * T[8 + j]);
    }
    char* asb = smem + buf * 8192;
    *(bf16x8*)(asb + wb0) = v0;
    *(bf16x8*)(asb + wb1) = v1;
  };

  STAGE(0, 0);
  GENA(0, 0);
  asm volatile("s_waitcnt vmcnt(0) lgkmcnt(0)" ::: "memory");
  __builtin_amdgcn_s_barrier();

  const int rA = lane & 15, sg = lane >> 4;
  const int soff = (sg ^ ((rA >> 1) & 3)) << 4;
  const int aoff = (wm * 64 + rA) * 64 + soff;   // + m*1024 bytes
  const int boff = (wn * 128 + rA) * 64 + soff;  // + n*1024 bytes

  for (int kk = 0; kk < NSTEP; ++kk) {
    const int cur = kk & 1;
    if (kk + 1 < NSTEP) {
      STAGE(kk + 1, cur ^ 1);
      GENA(kk + 1, cur ^ 1);
    }
    const char* ab = smem + cur * 8192;
    const char* bb = smem + 16384 + cur * 16384;
    bf16x8 a[4];
#pragma unroll
    for (int m = 0; m < 4; ++m)
      a[m] = __builtin_bit_cast(bf16x8, *(const s16x8*)(ab + aoff + m * 1024));
#pragma unroll
    for (int n = 0; n < 8; ++n) {
      bf16x8 bf = __builtin_bit_cast(bf16x8, *(const s16x8*)(bb + boff + n * 1024));
      acc[0][n] = __builtin_amdgcn_mfma_f32_16x16x32_bf16(a[0], bf, acc[0][n], 0, 0, 0);
      acc[1][n] = __builtin_amdgcn_mfma_f32_16x16x32_bf16(a[1], bf, acc[1][n], 0, 0, 0);
      acc[2][n] = __builtin_amdgcn_mfma_f32_16x16x32_bf16(a[2], bf, acc[2][n], 0, 0, 0);
      acc[3][n] = __builtin_amdgcn_mfma_f32_16x16x32_bf16(a[3], bf, acc[3][n], 0, 0, 0);
    }
    asm volatile("s_waitcnt vmcnt(0) lgkmcnt(0)" ::: "memory");
    __builtin_amdgcn_s_barrier();
  }

  // ---- epilogue: C/D map col=lane&15, row=(lane>>4)*4+reg ----
  const int c0 = lane & 15;
  const int r0 = (lane >> 4) * 4;
#pragma unroll
  for (int m = 0; m < 4; ++m)
#pragma unroll
    for (int n = 0; n < 8; ++n) {
      int col = bcol + wn * 128 + n * 16 + c0;
#pragma unroll
      for (int r = 0; r < 4; ++r)
        C[(size_t)(brow + wm * 64 + m * 16 + r0 + r) * NF + col] = acc[m][n][r];
    }
}

extern "C" void kernel_launch(void* const* d_in, const int* in_sizes, int n_in,
                              void* d_out, int out_size, void* d_ws, size_t ws_size,
                              hipStream_t stream) {
  const float* x  = (const float*)d_in[0];
  const float* fw = (const float*)d_in[1];
  const float* th = (const float*)d_in[2];
  const float* lv = (const float*)d_in[3];
  float* out = (float*)d_out;

  float* probs = (float*)d_ws;                           // 20 KB
  u16* lvb = (u16*)((char*)d_ws + DEPTH * NF * 4);       // 1 MB
  float* pbuf = (float*)((char*)d_ws + DEPTH * NF * 4 + NF * NL * 2);  // 1.3 MB

  k_softmax<<<1, 640, 0, stream>>>(fw, probs);
  k_cvt<<<(NF * NL / 8) / 256, 256, 0, stream>>>(lv, lvb);
  k_sel<<<BATCH_N / 16, 256, 0, stream>>>(x, probs, th, pbuf);
  k_gemm<<<(BATCH_N / GBM) * 2, 256, 0, stream>>>(lvb, pbuf, out);
}

// Round 8
// 64.302 us; speedup vs baseline: 2.1035x; 1.2512x over previous
//
#include <hip/hip_runtime.h>
#include <hip/hip_bf16.h>
#include <cstdint>

using u16 = unsigned short;
using u32 = unsigned int;

#define DEPTH 10
#define NF 512
#define NL 1024
#define BATCH_N 32768
#define TEMP_INV 10.0f
#define GBM 128
#define GBN 256
#define GBK 32
#define NSTEP 32

typedef float f32x4 __attribute__((ext_vector_type(4)));
typedef short s16x8 __attribute__((ext_vector_type(8)));
typedef __bf16 bf16x8 __attribute__((ext_vector_type(8)));

__device__ __forceinline__ u16 f2bf(float f) {
  u32 u = __float_as_uint(f);
  u = (u + 0x7fffu + ((u >> 16) & 1u)) >> 16;
  return (u16)u;
}

__device__ __forceinline__ void gld_lds16(const void* g, void* lds) {
  __builtin_amdgcn_global_load_lds(
      (const __attribute__((address_space(1))) void*)g,
      (__attribute__((address_space(3))) void*)lds, 16, 0, 0);
}

// ---------------- kernel 1: leaf_values f32 (512x1024) -> bf16 (same layout)
__global__ void k_cvt(const float* __restrict__ lv, u16* __restrict__ lvb) {
  int i = (blockIdx.x * blockDim.x + threadIdx.x) * 8;
  float4 a = *(const float4*)(lv + i);
  float4 b = *(const float4*)(lv + i + 4);
  uint4 u;
  u.x = f2bf(a.x) | ((u32)f2bf(a.y) << 16);
  u.y = f2bf(a.z) | ((u32)f2bf(a.w) << 16);
  u.z = f2bf(b.x) | ((u32)f2bf(b.y) << 16);
  u.w = f2bf(b.z) | ((u32)f2bf(b.w) << 16);
  *(uint4*)(lvb + i) = u;
}

// ---------------- kernel 2: softmax(fw) in-block + sel -> sigmoid -> p[32768][10]
// lane g owns features i*64+g*4..+3 (contiguous 256B per 16-lane group);
// 2 rows/thread (halves Ps LDS traffic); 4-level shfl reduce over g.
__global__ __launch_bounds__(256, 4) void k_sel(const float* __restrict__ x,
                                                const float* __restrict__ fw,
                                                const float* __restrict__ thr,
                                                float* __restrict__ pout) {
  __shared__ float Ps[DEPTH * NF];  // 20 KB, plain [10][512]
  const int tid = threadIdx.x;
  const int lane = tid & 63;
  const int w = tid >> 6;

  // --- per-block softmax of fw rows (wave w handles d = w, w+4, w+8) ---
  for (int d = w; d < DEPTH; d += 4) {
    const float* row = fw + d * NF;
    float v[8];
    float mx = -1e30f;
#pragma unroll
    for (int i = 0; i < 8; ++i) { v[i] = row[lane * 8 + i]; mx = fmaxf(mx, v[i]); }
#pragma unroll
    for (int s = 32; s >= 1; s >>= 1) mx = fmaxf(mx, __shfl_xor(mx, s));
    float sum = 0.f;
#pragma unroll
    for (int i = 0; i < 8; ++i) { v[i] = __expf(v[i] - mx); sum += v[i]; }
#pragma unroll
    for (int s = 32; s >= 1; s >>= 1) sum += __shfl_xor(sum, s);
    float inv = 1.0f / sum;
#pragma unroll
    for (int i = 0; i < 8; ++i) Ps[d * NF + lane * 8 + i] = v[i] * inv;
  }
  __syncthreads();

  const int g = lane & 15;
  const int qr = lane >> 4;
  const int r0 = blockIdx.x * 32 + (w * 4 + qr) * 2;
  const float* xp0 = x + (size_t)r0 * NF + g * 4;
  const float* xp1 = xp0 + NF;

  float a0[DEPTH], a1[DEPTH];
#pragma unroll
  for (int d = 0; d < DEPTH; ++d) { a0[d] = 0.f; a1[d] = 0.f; }
#pragma unroll 2
  for (int i = 0; i < 8; ++i) {
    float4 xv0 = *(const float4*)(xp0 + i * 64);
    float4 xv1 = *(const float4*)(xp1 + i * 64);
    const float* pb = &Ps[i * 64 + g * 4];
#pragma unroll
    for (int d = 0; d < DEPTH; ++d) {
      f32x4 pv = *(const f32x4*)(pb + d * NF);
      a0[d] += xv0.x * pv[0] + xv0.y * pv[1] + xv0.z * pv[2] + xv0.w * pv[3];
      a1[d] += xv1.x * pv[0] + xv1.y * pv[1] + xv1.z * pv[2] + xv1.w * pv[3];
    }
  }
#pragma unroll
  for (int d = 0; d < DEPTH; ++d) {
    a0[d] += __shfl_xor(a0[d], 1); a0[d] += __shfl_xor(a0[d], 2);
    a0[d] += __shfl_xor(a0[d], 4); a0[d] += __shfl_xor(a0[d], 8);
    a1[d] += __shfl_xor(a1[d], 1); a1[d] += __shfl_xor(a1[d], 2);
    a1[d] += __shfl_xor(a1[d], 4); a1[d] += __shfl_xor(a1[d], 8);
  }
  if (g < DEPTH) {
    float s0 = (g == 0) ? a0[0] : (g == 1) ? a0[1] : (g == 2) ? a0[2]
             : (g == 3) ? a0[3] : (g == 4) ? a0[4] : (g == 5) ? a0[5]
             : (g == 6) ? a0[6] : (g == 7) ? a0[7] : (g == 8) ? a0[8] : a0[9];
    float s1 = (g == 0) ? a1[0] : (g == 1) ? a1[1] : (g == 2) ? a1[2]
             : (g == 3) ? a1[3] : (g == 4) ? a1[4] : (g == 5) ? a1[5]
             : (g == 6) ? a1[6] : (g == 7) ? a1[7] : (g == 8) ? a1[8] : a1[9];
    float t = thr[g];
    pout[(size_t)r0 * DEPTH + g]       = 1.0f / (1.0f + __expf(-(s0 - t) * TEMP_INV));
    pout[(size_t)(r0 + 1) * DEPTH + g] = 1.0f / (1.0f + __expf(-(s1 - t) * TEMP_INV));
  }
}

// ---------------- kernel 3: GEMM  C[128x256 tile] = leafprob(gen) @ lvb^T
// 3-deep B-buffer (3x16KB), counted vmcnt(4); As double-buffer 2x8KB @49152.
// One barrier/step; STAGE(k+2) issued right after the barrier.
__global__ __launch_bounds__(256, 2) void k_gemm(const u16* __restrict__ B,
                                                 const float* __restrict__ p,
                                                 float* __restrict__ C) {
  __shared__ char smem[65536];  // Bs: 3x16KB @0, As: 2x8KB @49152
  const int tid = threadIdx.x;
  const int lane = tid & 63;
  const int w = tid >> 6;       // 0..3
  const int wm = w >> 1, wn = w & 1;
  const int bm = blockIdx.x >> 1, bn = blockIdx.x & 1;
  const int brow = bm * GBM, bcol = bn * GBN;

  // ---- A-generator identity: thread owns row gr, leaf-half gh ----
  const int gr = tid >> 1;   // 0..127
  const int gh = tid & 1;    // leaf bit b4 (d=5)
  const float* prw = p + (size_t)(brow + gr) * DEPTH;
  float pv[10];
#pragma unroll
  for (int d = 0; d < 10; ++d) pv[d] = prw[d];
  float T[16];
  {
    float s5 = gh ? pv[5] : 1.f - pv[5];
    float a6 = 1.f - pv[6], b6 = pv[6], a7 = 1.f - pv[7], b7 = pv[7];
    float a8 = 1.f - pv[8], b8 = pv[8], a9 = 1.f - pv[9], b9 = pv[9];
    float m67[4] = {a6 * a7, a6 * b7, b6 * a7, b6 * b7};
    float m89[4] = {a8 * a9, a8 * b9, b8 * a9, b8 * b9};
#pragma unroll
    for (int i = 0; i < 16; ++i) T[i] = s5 * m67[i >> 2] * m89[i & 3];
  }
  const float p0a = 1.f - pv[0], p0b = pv[0], p1a = 1.f - pv[1], p1b = pv[1],
              p2a = 1.f - pv[2], p2b = pv[2], p3a = 1.f - pv[3], p3b = pv[3],
              p4a = 1.f - pv[4], p4b = pv[4];

  const int xorg = (gr >> 1) & 3;
  const int wb0 = gr * 64 + (((gh * 2)     ^ xorg) << 4);
  const int wb1 = gr * 64 + (((gh * 2 + 1) ^ xorg) << 4);

  f32x4 acc[4][8];
#pragma unroll
  for (int m = 0; m < 4; ++m)
#pragma unroll
    for (int n = 0; n < 8; ++n) acc[m][n] = {0.f, 0.f, 0.f, 0.f};

  auto STAGE = [&](int step, int buf) {
    char* bsb = smem + buf * 16384;
#pragma unroll
    for (int it = 0; it < 4; ++it) {
      int lin = it * 256 + tid;
      int r = lin >> 2;
      int slog = (lin & 3) ^ ((r >> 1) & 3);
      gld_lds16(B + (size_t)(bcol + r) * NL + step * GBK + slog * 8, bsb + lin * 16);
    }
  };
  auto GENA = [&](int step, int buf) {
    float H = ((step & 16) ? p0b : p0a) * ((step & 8) ? p1b : p1a);
    H *= (step & 4) ? p2b : p2a;
    H *= (step & 2) ? p3b : p3a;
    H *= (step & 1) ? p4b : p4a;
    bf16x8 v0, v1;
#pragma unroll
    for (int j = 0; j < 8; ++j) {
      v0[j] = (__bf16)(H * T[j]);
      v1[j] = (__bf16)(H * T[8 + j]);
    }
    char* asb = smem + 49152 + buf * 8192;   // 8 KB per A buffer (128 rows x 64 B)
    *(bf16x8*)(asb + wb0) = v0;
    *(bf16x8*)(asb + wb1) = v1;
  };

  const int rA = lane & 15, sg = lane >> 4;
  const int soff = (sg ^ ((rA >> 1) & 3)) << 4;
  const int aoff = (wm * 64 + rA) * 64 + soff;   // + m*1024 bytes
  const int boff = (wn * 128 + rA) * 64 + soff;  // + n*1024 bytes

  auto DOMFMA = [&](int bbuf, int abuf) {
    const char* ab = smem + 49152 + abuf * 8192;
    const char* bb = smem + bbuf * 16384;
    bf16x8 a[4];
#pragma unroll
    for (int m = 0; m < 4; ++m)
      a[m] = __builtin_bit_cast(bf16x8, *(const s16x8*)(ab + aoff + m * 1024));
#pragma unroll
    for (int n = 0; n < 8; ++n) {
      bf16x8 bf = __builtin_bit_cast(bf16x8, *(const s16x8*)(bb + boff + n * 1024));
      acc[0][n] = __builtin_amdgcn_mfma_f32_16x16x32_bf16(a[0], bf, acc[0][n], 0, 0, 0);
      acc[1][n] = __builtin_amdgcn_mfma_f32_16x16x32_bf16(a[1], bf, acc[1][n], 0, 0, 0);
      acc[2][n] = __builtin_amdgcn_mfma_f32_16x16x32_bf16(a[2], bf, acc[2][n], 0, 0, 0);
      acc[3][n] = __builtin_amdgcn_mfma_f32_16x16x32_bf16(a[3], bf, acc[3][n], 0, 0, 0);
    }
  };

  // prologue: stage steps 0,1; gen A(0)
  STAGE(0, 0);
  GENA(0, 0);
  STAGE(1, 1);

  int bcur = 0, bpre = 2;
  for (int kk = 0; kk < NSTEP - 1; ++kk) {
    // stage(kk) complete (4 = stage(kk+1) still in flight); A(kk)+prev reads drained
    asm volatile("s_waitcnt vmcnt(4) lgkmcnt(0)" ::: "memory");
    __builtin_amdgcn_s_barrier();
    __builtin_amdgcn_sched_barrier(0);  // keep ds ops below the barrier
    if (kk < NSTEP - 2) STAGE(kk + 2, bpre);
    GENA(kk + 1, (kk + 1) & 1);
    DOMFMA(bcur, kk & 1);
    bcur = (bcur == 2) ? 0 : bcur + 1;
    bpre = (bpre == 2) ? 0 : bpre + 1;
  }
  asm volatile("s_waitcnt vmcnt(0) lgkmcnt(0)" ::: "memory");
  __builtin_amdgcn_s_barrier();
  __builtin_amdgcn_sched_barrier(0);
  DOMFMA(bcur, (NSTEP - 1) & 1);

  // ---- epilogue: C/D map col=lane&15, row=(lane>>4)*4+reg ----
  const int c0 = lane & 15;
  const int r0 = (lane >> 4) * 4;
#pragma unroll
  for (int m = 0; m < 4; ++m)
#pragma unroll
    for (int n = 0; n < 8; ++n) {
      int col = bcol + wn * 128 + n * 16 + c0;
#pragma unroll
      for (int r = 0; r < 4; ++r)
        C[(size_t)(brow + wm * 64 + m * 16 + r0 + r) * NF + col] = acc[m][n][r];
    }
}

extern "C" void kernel_launch(void* const* d_in, const int* in_sizes, int n_in,
                              void* d_out, int out_size, void* d_ws, size_t ws_size,
                              hipStream_t stream) {
  const float* x  = (const float*)d_in[0];
  const float* fw = (const float*)d_in[1];
  const float* th = (const float*)d_in[2];
  const float* lv = (const float*)d_in[3];
  float* out = (float*)d_out;

  u16* lvb = (u16*)d_ws;                                  // 1 MB
  float* pbuf = (float*)((char*)d_ws + NF * NL * 2);      // 1.3 MB

  k_cvt<<<(NF * NL / 8) / 256, 256, 0, stream>>>(lv, lvb);
  k_sel<<<BATCH_N / 32, 256, 0, stream>>>(x, fw, th, pbuf);
  k_gemm<<<(BATCH_N / GBM) * 2, 256, 0, stream>>>(lvb, pbuf, out);
}